// Round 1
// baseline (988.202 us; speedup 1.0000x reference)
//
#include <hip/hip_runtime.h>
#include <math.h>

#define NN 20000
#define EE 100000
#define FIN 167
#define KP1 256    // layer-1 K padded to mult of 128 (BK=64, 2 tiles/dbuf pair)
#define HID 1024   // H*O = 4*256
#define OO 256
#define NB 16      // nodes per k_gath block

typedef unsigned short u16;
typedef short bf16x8 __attribute__((ext_vector_type(8)));
typedef float f32x4  __attribute__((ext_vector_type(4)));

__device__ __forceinline__ float bf(u16 u){ return __uint_as_float(((unsigned)u)<<16); }
__device__ __forceinline__ u16 fb(float v){            // f32 -> bf16 RNE
  unsigned u = __float_as_uint(v);
  return (u16)((u + 0x7FFFu + ((u>>16)&1u)) >> 16);
}
__device__ __forceinline__ float ldv(const float* p, long i){ return p[i]; }
__device__ __forceinline__ float ldv(const u16*   p, long i){ return bf(p[i]); }

// ---------------- CSR build ----------------
__global__ void k_count(const int* __restrict__ ei, int* __restrict__ counts){
  int e = blockIdx.x*256 + threadIdx.x;
  if (e < EE) atomicAdd(&counts[ei[EE+e]], 1);
}

__global__ __launch_bounds__(256) void k_scan(const int* __restrict__ counts, int* __restrict__ iptr){
  __shared__ int sd[256];
  int tid = threadIdx.x;
  int carry = 0;
  for (int base=0; base<NN; base+=256){
    int i = base+tid;
    int v = (i<NN)? counts[i] : 0;
    sd[tid]=v;
    __syncthreads();
    for (int off=1; off<256; off<<=1){
      int t = (tid>=off)? sd[tid-off] : 0;
      __syncthreads();
      sd[tid] += t;
      __syncthreads();
    }
    if (i<NN) iptr[i] = carry + sd[tid] - v;
    carry += sd[255];
    __syncthreads();
  }
  if (tid==0) iptr[NN]=carry;
}

__global__ void k_fill(const int* __restrict__ ei, const int* __restrict__ iptr,
                       int* __restrict__ cursor, int* __restrict__ eid){
  int e = blockIdx.x*256 + threadIdx.x;
  if (e < EE){
    int d = ei[EE+e];
    int pos = atomicAdd(&cursor[d],1);
    eid[iptr[d]+pos] = e;
  }
}

// ---------------- BatchNorm stats ----------------
template<typename T>
__global__ void k_bnstats(const T* __restrict__ X, float* __restrict__ sums, int F){
  int f = blockIdx.y*256 + threadIdx.x;
  if (f >= F) return;
  int r0 = blockIdx.x*100, r1 = r0+100;
  float s=0.f, s2=0.f;
  for (int r=r0;r<r1;r++){ float v = ldv(X,(long)r*F+f); s += v; s2 += v*v; }
  atomicAdd(&sums[f], s);
  atomicAdd(&sums[F+f], s2);
}

__global__ void k_bnfin(const float* __restrict__ sums, const float* __restrict__ g,
                        const float* __restrict__ b, float* __restrict__ scale,
                        float* __restrict__ shift, int F){
  int f = blockIdx.x*256 + threadIdx.x;
  if (f >= F) return;
  float mu  = sums[f]   * (1.f/NN);
  float var = sums[F+f] * (1.f/NN) - mu*mu;
  float sc  = rsqrtf(var + 1e-5f) * g[f];
  scale[f] = sc;
  shift[f] = b[f] - mu*sc;
}

// ---------------- BN-folded fused weight prep ----------------
__global__ __launch_bounds__(256) void k_foldT(const float* __restrict__ Wg, const float* __restrict__ Wl,
                        const float* __restrict__ scale,
                        u16* __restrict__ Wt, int K, int Kp){
  __shared__ float t[32][33];
  int k0 = blockIdx.x*32, c0 = blockIdx.y*32;
  int tx = threadIdx.x & 31, ty = threadIdx.x >> 5;
  bool second = (c0 >= HID);
  const float* W = second ? Wl : Wg;
  int cc0 = second ? c0 - HID : c0;
  #pragma unroll
  for (int i=0;i<4;i++){
    int k = k0 + ty + i*8;
    t[ty+i*8][tx] = (k < K) ? W[(long)k*HID + cc0 + tx] * scale[k] : 0.f;
  }
  __syncthreads();
  #pragma unroll
  for (int i=0;i<4;i++){
    int c = c0 + ty + i*8;
    Wt[(long)c*Kp + k0 + tx] = fb(t[tx][ty+i*8]);
  }
}

// cst init: lb for lin half, 0 for hg half
__global__ void k_cinit(const float* __restrict__ lb, float* __restrict__ cst){
  int c = blockIdx.x*256 + threadIdx.x;
  if (c < 2*HID) cst[c] = (c >= HID) ? lb[c-HID] : 0.f;
}

// cst[c] += sum_k shift[k]*W[k][c]  — parallel reduction, coalesced
__global__ __launch_bounds__(256) void k_const(const float* __restrict__ Wg, const float* __restrict__ Wl,
                        const float* __restrict__ shift, float* __restrict__ cst, int K){
  int tx = threadIdx.x & 63, ty = threadIdx.x >> 6;
  int c = blockIdx.x*64 + tx;
  bool second = c >= HID;
  const float* W = second ? Wl : Wg;
  int cc = second ? c-HID : c;
  int k0 = blockIdx.y*128;
  int k1 = min(K, k0+128);
  float s = 0.f;
  for (int k=k0+ty; k<k1; k+=4) s += shift[k]*W[(long)k*HID+cc];
  __shared__ float red[256];
  red[threadIdx.x] = s;
  __syncthreads();
  if (ty == 0){
    float tot = red[tx] + red[tx+64] + red[tx+128] + red[tx+192];
    atomicAdd(&cst[c], tot);
  }
}

__global__ void k_cast(const float* __restrict__ x, u16* __restrict__ xb){
  long idx = (long)blockIdx.x*256 + threadIdx.x;
  if (idx >= (long)NN*KP1) return;
  int n = (int)(idx / KP1), k = (int)(idx % KP1);
  xb[idx] = (k<FIN)? fb(x[(long)n*FIN+k]) : (u16)0;
}

__global__ void k_we16(const float* __restrict__ We, u16* __restrict__ We16){
  int i = blockIdx.x*256 + threadIdx.x;
  if (i < 10*HID) We16[i] = fb(We[i]);
}

// ---------------- MFMA GEMM v2: 256x128 tile, BK=64, 8 waves, counted-vmcnt ----------------
// T3+T4 phase schedule (learn_hip 8-phase template, tile shrunk to 256x128 so the grid is
// 79*16 = 1264 blocks = 4.94 rounds on 256 CUs -> 99% tail efficiency).
// Double-buffered LDS (96 KB, 1 block/CU). Raw s_barrier (NOT __syncthreads) so staging
// loads stay in flight across the tile; vmcnt(0) only at tile top, waiting loads that
// were issued one full tile (~2 phases of 16 MFMA + barriers) earlier.
// T2 both-sides swizzle: LDS linear (global_load_lds dest must be base+lane*16, m104);
// GLOBAL source chunk is pre-permuted  chunk ^= (row&7)  and ds_read applies the same XOR
// -> each 4-bank group serves exactly 8 lanes per ds_read_b128 (bank-optimal).
// T5 setprio around the MFMA clusters (pays only on phased schedules).
#define STAGE(KT_, CB_) do {                                                        \
    int k0_ = (KT_) << 6;                                                           \
    _Pragma("unroll")                                                               \
    for (int i_=0;i_<4;i_++)                                                        \
      __builtin_amdgcn_global_load_lds(Ap[i_]+k0_, &Asm[CB_][i_*4096+wave*512], 16, 0, 0); \
    _Pragma("unroll")                                                               \
    for (int j_=0;j_<2;j_++)                                                        \
      __builtin_amdgcn_global_load_lds(Bp[j_]+k0_, &Bsm[CB_][j_*4096+wave*512], 16, 0, 0); \
  } while(0)

#define GTILE(T_, CB_) do {                                                         \
    asm volatile("s_waitcnt vmcnt(0)" ::: "memory");                                \
    __builtin_amdgcn_s_barrier();                                                   \
    asm volatile("" ::: "memory");                                                  \
    const u16* Ab_ = &Asm[CB_][abase];                                              \
    const u16* Bb_ = &Bsm[CB_][bbase];                                              \
    bf16x8 a0_[4], b0_[4], a1_[4], b1_[4];                                          \
    _Pragma("unroll")                                                               \
    for (int i_=0;i_<4;i_++) a0_[i_] = *(const bf16x8*)(Ab_ + i_*1024 + swz0);      \
    _Pragma("unroll")                                                               \
    for (int j_=0;j_<4;j_++) b0_[j_] = *(const bf16x8*)(Bb_ + j_*1024 + swz0);      \
    if ((T_)+1 < NT) { STAGE((T_)+1, (CB_)^1); }                                    \
    __builtin_amdgcn_s_barrier();                                                   \
    asm volatile("s_waitcnt lgkmcnt(0)" ::: "memory");                              \
    __builtin_amdgcn_s_setprio(1);                                                  \
    _Pragma("unroll")                                                               \
    for (int i_=0;i_<4;i_++)                                                        \
      _Pragma("unroll")                                                             \
      for (int j_=0;j_<4;j_++)                                                      \
        acc[i_][j_] = __builtin_amdgcn_mfma_f32_16x16x32_bf16(a0_[i_], b0_[j_], acc[i_][j_], 0,0,0); \
    __builtin_amdgcn_s_setprio(0);                                                  \
    __builtin_amdgcn_s_barrier();                                                   \
    asm volatile("" ::: "memory");                                                  \
    _Pragma("unroll")                                                               \
    for (int i_=0;i_<4;i_++) a1_[i_] = *(const bf16x8*)(Ab_ + i_*1024 + swz1);      \
    _Pragma("unroll")                                                               \
    for (int j_=0;j_<4;j_++) b1_[j_] = *(const bf16x8*)(Bb_ + j_*1024 + swz1);      \
    __builtin_amdgcn_s_barrier();                                                   \
    asm volatile("s_waitcnt lgkmcnt(0)" ::: "memory");                              \
    __builtin_amdgcn_s_setprio(1);                                                  \
    _Pragma("unroll")                                                               \
    for (int i_=0;i_<4;i_++)                                                        \
      _Pragma("unroll")                                                             \
      for (int j_=0;j_<4;j_++)                                                      \
        acc[i_][j_] = __builtin_amdgcn_mfma_f32_16x16x32_bf16(a1_[i_], b1_[j_], acc[i_][j_], 0,0,0); \
    __builtin_amdgcn_s_setprio(0);                                                  \
  } while(0)

__global__ __launch_bounds__(512,2) void k_gemm(const u16* __restrict__ A, int K,
                     const u16* __restrict__ Wt, const float* __restrict__ cst,
                     u16* __restrict__ Chg, u16* __restrict__ Clin){
  __shared__ u16 Asm[2][16384];   // 2 x (256 rows x 64 k) = 64 KB
  __shared__ u16 Bsm[2][8192];    // 2 x (128 cols x 64 k) = 32 KB
  int b = blockIdx.x;
  int wg = (b & 7)*158 + (b >> 3);          // XCD swizzle; 1264 % 8 == 0 -> bijective
  int row0 = (wg >> 4)*256, col0 = (wg & 15)*128;
  int tid = threadIdx.x;
  int wave = tid >> 6, lane = tid & 63, quad = lane >> 4, lo = lane & 15;
  int wm = wave >> 1, wn = wave & 1;        // 4 M-waves x 2 N-waves, 64x64 out each
  // staging: slot s = i*512 + tid ; row = s>>3 ; chunk = s&7 ; src chunk = chunk^(row&7)
  int srow = tid >> 3, schk = tid & 7;
  int sg = (schk ^ (srow & 7)) * 8;         // u16 offset of pre-swizzled 16B chunk
  const u16* Ap[4];
  const u16* Bp[2];
  #pragma unroll
  for (int i=0;i<4;i++){
    int r = row0 + i*64 + srow; if (r >= NN) r = NN-1;   // clamp: garbage rows never stored
    Ap[i] = A + (long)r*K + sg;
  }
  #pragma unroll
  for (int j=0;j<2;j++){
    Bp[j] = Wt + (long)(col0 + j*64 + srow)*K + sg;
  }
  // fragment read addressing (same XOR as the staging pre-swizzle)
  int abase = (wm*64 + lo)*64;
  int bbase = (wn*64 + lo)*64;
  int swz0 = ( quad      ^ (lo & 7))*8;     // kk=0: chunk pos = quad
  int swz1 = ((4 + quad) ^ (lo & 7))*8;     // kk=1: chunk pos = 4+quad
  int NT = K >> 6;
  f32x4 acc[4][4] = {};
  STAGE(0, 0);
  for (int tt=0; tt<NT; tt+=2){
    GTILE(tt,   0);
    GTILE(tt+1, 1);
  }
  #pragma unroll
  for (int i=0;i<4;i++){
    #pragma unroll
    for (int t=0;t<4;t++){
      int col = col0 + wn*64 + t*16 + lo;
      float cs = cst[col];
      #pragma unroll
      for (int r=0;r<4;r++){
        int row = row0 + wm*64 + i*16 + quad*4 + r;   // C/D: col=lane&15, row=quad*4+reg
        if (row < NN){
          u16 o = fb(acc[i][t][r] + cs);
          if (col < HID) Chg[(long)row*HID + col] = o;
          else           Clin[(long)row*HID + col - HID] = o;
        }
      }
    }
  }
}
#undef GTILE
#undef STAGE

// ---------------- per-(node,head) attention dots ----------------
__global__ void k_sdot(const u16* __restrict__ hg, const float* __restrict__ attn,
                       float* __restrict__ ssrc, float* __restrict__ sdst){
  int idx = blockIdx.x*256 + threadIdx.x;
  if (idx >= NN*4) return;
  int n = idx >> 2, h = idx & 3;
  const u16* hp = hg + (long)n*HID + h*OO;
  const float* a0 = attn + h*OO;
  const float* a1 = attn + HID + h*OO;
  float ss=0.f, sd=0.f;
  for (int d=0;d<OO;d++){ float v = bf(hp[d]); ss += v*a0[d]; sd += v*a1[d]; }
  ssrc[idx]=ss; sdst[idx]=sd;
}

__global__ void k_q(const float* __restrict__ We, const float* __restrict__ attn,
                    float* __restrict__ q){
  int t = threadIdx.x;
  if (t >= 40) return;
  int k = t >> 2, h = t & 3;
  float s = 0.f;
  for (int d=0; d<OO; d++) s += We[(long)k*HID + h*OO + d] * attn[2*HID + h*OO + d];
  q[k*4+h] = s;
}

__global__ void k_logits(const int* __restrict__ ei, const float* __restrict__ ea,
                         const float* __restrict__ q, const float* __restrict__ at,
                         const float* __restrict__ ssrc, const float* __restrict__ sdst,
                         float* __restrict__ L){
  int idx = blockIdx.x*256 + threadIdx.x;
  if (idx >= EE*4) return;
  int e = idx >> 2, h = idx & 3;
  int s = ei[e], dd = ei[EE+e];
  float se = 0.f;
  #pragma unroll
  for (int k=0;k<10;k++) se += ea[e*12+1+k] * q[k*4+h];
  float v = ssrc[s*4+h] + sdst[dd*4+h] + se + ea[e*12]*at[h];
  L[idx] = (v>0.f)? v : 0.2f*v;
}

__global__ void k_mden(const int* __restrict__ iptr, const int* __restrict__ eid,
                       const float* __restrict__ L, float* __restrict__ m, float* __restrict__ dinv){
  int idx = blockIdx.x*256 + threadIdx.x;
  if (idx >= NN*4) return;
  int n = idx >> 2, h = idx & 3;
  int b = iptr[n], e1 = iptr[n+1];
  float mx = -INFINITY;
  for (int i=b;i<e1;i++) mx = fmaxf(mx, L[eid[i]*4+h]);
  if (b == e1) mx = 0.f;
  float s = 0.f;
  for (int i=b;i<e1;i++) s += expf(L[eid[i]*4+h] - mx);
  m[idx] = mx;
  dinv[idx] = 1.f/(s + 1e-16f);
}

// ---------------- edge gather: NB nodes per block, We bf16 in LDS ----------------
__global__ __launch_bounds__(256) void k_gath(
    const u16* __restrict__ hg, const int* __restrict__ ei,
    const float* __restrict__ ea, const int* __restrict__ iptr,
    const int* __restrict__ eid, const float* __restrict__ L,
    const float* __restrict__ m, const float* __restrict__ dinv,
    const u16* __restrict__ We16, const float* __restrict__ cb,
    u16* __restrict__ lio)
{
  __shared__ u16  sWe[10*HID];   // 20 KB
  __shared__ float scb[HID];     // 4 KB
  int tid = threadIdx.x;
  for (int i=tid;i<10*HID;i+=256) sWe[i] = We16[i];
  for (int i=tid;i<HID;i+=256) scb[i] = cb[i];
  __syncthreads();
  int d0 = blockIdx.x*NB, dend = min(NN, d0+NB);
  for (int d=d0; d<dend; d++){
    float acc[4];
    #pragma unroll
    for (int j=0;j<4;j++) acc[j] = bf(lio[(long)d*HID + tid + j*256]);
    int b0 = iptr[d], en = iptr[d+1];
    float mm[4], dv[4];
    #pragma unroll
    for (int j=0;j<4;j++){ mm[j]=m[d*4+j]; dv[j]=dinv[d*4+j]; }
    for (int i=b0;i<en;i++){
      int e = eid[i], s_ = ei[e];
      float c10[10];
      #pragma unroll
      for (int k=0;k<10;k++) c10[k] = ea[e*12+1+k];
      float w4[4];
      #pragma unroll
      for (int j=0;j<4;j++) w4[j] = expf(L[e*4+j]-mm[j])*dv[j];
      const u16* hgs = hg + (long)s_*HID + tid;
      #pragma unroll
      for (int j=0;j<4;j++){
        int f = tid + j*256;
        float ew = 0.f;
        #pragma unroll
        for (int k=0;k<10;k++) ew += c10[k]*bf(sWe[k*HID+f]);
        acc[j] += w4[j]*(bf(hgs[j*256]) + ew);
      }
    }
    #pragma unroll
    for (int j=0;j<4;j++){
      int f = tid + j*256;
      lio[(long)d*HID+f] = fb(fmaxf(acc[j] + scb[f], 0.f));
    }
  }
}

// ---------------- layer 3 ----------------
__global__ __launch_bounds__(256) void k_n3(
    const u16* __restrict__ in, const float* __restrict__ scale, const float* __restrict__ shift,
    const float* __restrict__ Wg, const float* __restrict__ lw, const float* __restrict__ lb,
    const float* __restrict__ attn,
    float* __restrict__ hg3, float* __restrict__ lin3,
    float* __restrict__ ssrc, float* __restrict__ sdst)
{
  __shared__ float xin[1024];
  __shared__ float red[256];
  int n = blockIdx.x, tid = threadIdx.x;
  for (int k=tid;k<HID;k+=256) xin[k] = bf(in[(long)n*HID+k])*scale[k]+shift[k];
  __syncthreads();
  float p[4] = {0.f,0.f,0.f,0.f};
  for (int k=tid;k<HID;k+=256){
    float xv = xin[k];
    p[0] += xv*Wg[k*2];   p[1] += xv*Wg[k*2+1];
    p[2] += xv*lw[k*2];   p[3] += xv*lw[k*2+1];
  }
  float r[4];
  for (int q=0;q<4;q++){
    red[tid]=p[q]; __syncthreads();
    for (int o=128;o>0;o>>=1){ if(tid<o) red[tid]+=red[tid+o]; __syncthreads(); }
    r[q]=red[0]; __syncthreads();
  }
  if (tid==0){
    hg3[n*2]   = r[0];
    hg3[n*2+1] = r[1];
    lin3[n*2]   = r[2] + lb[0];
    lin3[n*2+1] = r[3] + lb[1];
    ssrc[n] = r[0]*attn[0] + r[1]*attn[1];
    sdst[n] = r[0]*attn[2] + r[1]*attn[3];
  }
}

__global__ void k_logits3(const int* __restrict__ ei, const float* __restrict__ ea,
                          const float* __restrict__ We, const float* __restrict__ attn,
                          const float* __restrict__ at, const float* __restrict__ ssrc,
                          const float* __restrict__ sdst, float* __restrict__ L){
  int e = blockIdx.x*256 + threadIdx.x;
  if (e >= EE) return;
  int s = ei[e], d = ei[EE+e];
  float e0=0.f, e1=0.f;
  #pragma unroll
  for (int k=0;k<10;k++){
    float c = ea[e*12+1+k];
    e0 += c*We[k*2]; e1 += c*We[k*2+1];
  }
  float se = e0*attn[4] + e1*attn[5];
  float v = ssrc[s] + sdst[d] + se + ea[e*12]*at[0];
  L[e] = (v>0.f)? v : 0.2f*v;
}

__global__ void k_mden3(const int* __restrict__ iptr, const int* __restrict__ eid,
                        const float* __restrict__ L, float* __restrict__ m, float* __restrict__ dinv){
  int n = blockIdx.x*256 + threadIdx.x;
  if (n >= NN) return;
  int b = iptr[n], e1 = iptr[n+1];
  float mx = -INFINITY;
  for (int i=b;i<e1;i++) mx = fmaxf(mx, L[eid[i]]);
  if (b == e1) mx = 0.f;
  float s = 0.f;
  for (int i=b;i<e1;i++) s += expf(L[eid[i]] - mx);
  m[n]=mx; dinv[n]=1.f/(s+1e-16f);
}

__global__ void k_gather3(const int* __restrict__ ei, const float* __restrict__ ea,
                          const int* __restrict__ iptr, const int* __restrict__ eid,
                          const float* __restrict__ L, const float* __restrict__ m,
                          const float* __restrict__ dinv, const float* __restrict__ hg3,
                          const float* __restrict__ We, const float* __restrict__ lin3,
                          const float* __restrict__ cb, float* __restrict__ out){
  int n = blockIdx.x*256 + threadIdx.x;
  if (n >= NN) return;
  int b = iptr[n], en = iptr[n+1];
  float a0=0.f, a1=0.f;
  float mn = m[n], dv = dinv[n];
  for (int i=b;i<en;i++){
    int e = eid[i], s_ = ei[e];
    float w = expf(L[e]-mn)*dv;
    float e0=0.f, e1v=0.f;
    #pragma unroll
    for (int k=0;k<10;k++){
      float c = ea[e*12+1+k];
      e0 += c*We[k*2]; e1v += c*We[k*2+1];
    }
    a0 += w*(hg3[s_*2]+e0);
    a1 += w*(hg3[s_*2+1]+e1v);
  }
  out[n*2]   = fmaxf(lin3[n*2]  +a0+cb[0], 0.f);
  out[n*2+1] = fmaxf(lin3[n*2+1]+a1+cb[1], 0.f);
}

extern "C" void kernel_launch(void* const* d_in, const int* in_sizes, int n_in,
                              void* d_out, int out_size, void* d_ws, size_t ws_size,
                              hipStream_t stream){
  const int* ei = (const int*)d_in[1];

  long long sz[64];
  {
    const long long* s64 = (const long long*)(const void*)in_sizes;
    bool is64 = (n_in >= 2) && (in_sizes[0] == 3340000) && (in_sizes[1] == 0)
                && (s64[1] == 200000);
    for (int i=0;i<n_in && i<64;i++) sz[i] = is64 ? s64[i] : (long long)in_sizes[i];
  }

  int IWg[3], IWe[3], IAttn[3], IAt[3], ICb[3], ILw[3], ILb[3], IG[3], IB[3];
  if (n_in > 8 && sz[8] == (long long)HID*HID){ // setup_inputs() dict order
    for (int l=0;l<3;l++){
      IWg[l]=3+l*5; IWe[l]=4+l*5; IAttn[l]=5+l*5; IAt[l]=6+l*5; ICb[l]=7+l*5;
      ILw[l]=18+l*4; ILb[l]=19+l*4; IG[l]=20+l*4; IB[l]=21+l*4;
    }
  } else {
    int idx=3;
    for (int l=0;l<3;l++){
      IWg[l]=idx++; IWe[l]=idx++; IAttn[l]=idx++; IAt[l]=idx++; ICb[l]=idx++;
      ILw[l]=idx++; ILb[l]=idx++; IG[l]=idx++; IB[l]=idx++;
    }
  }
  #define FP(i) ((const float*)d_in[(i)])

  char* ws = (char*)d_ws;
  size_t off = 0;
  auto alloc = [&](size_t bytes)->void*{ void* p = ws + off; off += (bytes + 255) & ~(size_t)255; return p; };
  auto G = [](long n){ return (int)((n+255)/256); };

  u16*   buf0 = (u16*)  alloc((size_t)NN*HID*2);   // hg (bf16)
  u16*   bufA = (u16*)  alloc((size_t)NN*HID*2);   // layer-1 lin/result
  u16*   bufB = (u16*)  alloc((size_t)NN*HID*2);   // layer-2 lin/result
  u16*   xbf  = (u16*)  alloc((size_t)NN*KP1*2);   // layer-1 A (bf16, padded)
  u16*   Wt   = (u16*)  alloc((size_t)2*HID*HID*2);// fused folded weights [2048][K] K-major
  u16*   We16 = (u16*)  alloc((size_t)10*HID*2);
  float* cst  = (float*)alloc(2*HID*4);
  float* L    = (float*)alloc((size_t)EE*4*4);
  float* m    = (float*)alloc((size_t)NN*4*4);
  float* dinv = (float*)alloc((size_t)NN*4*4);
  float* ssrc = (float*)alloc((size_t)NN*4*4);
  float* sdst = (float*)alloc((size_t)NN*4*4);
  int*   iptr = (int*)  alloc((size_t)(NN+4)*4);
  int*   cnts = (int*)  alloc((size_t)NN*4);
  int*   eid  = (int*)  alloc((size_t)EE*4);
  float* stats= (float*)alloc(2*HID*4);
  float* scale= (float*)alloc(HID*4);
  float* shift= (float*)alloc(HID*4);
  float* qbuf = (float*)alloc(64*4);
  float* hg3  = (float*)alloc((size_t)NN*2*4);
  float* lin3 = (float*)alloc((size_t)NN*2*4);

  // ---- CSR by dst ----
  hipMemsetAsync(cnts, 0, NN*sizeof(int), stream);
  k_count<<<G(EE),256,0,stream>>>(ei, cnts);
  k_scan<<<1,256,0,stream>>>(cnts, iptr);
  hipMemsetAsync(cnts, 0, NN*sizeof(int), stream);
  k_fill<<<G(EE),256,0,stream>>>(ei, iptr, cnts, eid);

  int gg = 1264;   // 79 row-tiles (256 rows) x 16 col-tiles (128 cols), XCD-swizzled in-kernel

  // ---- layer 1 (A = bf16(x), Kp=256) ----
  {
    hipMemsetAsync(stats, 0, 2*FIN*sizeof(float), stream);
    dim3 bg(200, 1);
    k_bnstats<float><<<bg,256,0,stream>>>(FP(0), stats, FIN);
    k_bnfin<<<1,256,0,stream>>>(stats, FP(IG[0]), FP(IB[0]), scale, shift, FIN);
    k_cast<<<G((long)NN*KP1),256,0,stream>>>(FP(0), xbf);
    dim3 ft(KP1/32, 64);
    k_foldT<<<ft,256,0,stream>>>(FP(IWg[0]), FP(ILw[0]), scale, Wt, FIN, KP1);
    k_cinit<<<8,256,0,stream>>>(FP(ILb[0]), cst);
    dim3 cg(32, (FIN+127)/128);
    k_const<<<cg,256,0,stream>>>(FP(IWg[0]), FP(ILw[0]), shift, cst, FIN);
    k_we16<<<40,256,0,stream>>>(FP(IWe[0]), We16);
    k_gemm<<<gg,512,0,stream>>>(xbf, KP1, Wt, cst, buf0, bufA);
    k_sdot<<<G(NN*4),256,0,stream>>>(buf0, FP(IAttn[0]), ssrc, sdst);
    k_q<<<1,64,0,stream>>>(FP(IWe[0]), FP(IAttn[0]), qbuf);
    k_logits<<<G(EE*4),256,0,stream>>>(ei, FP(2), qbuf, FP(IAt[0]), ssrc, sdst, L);
    k_mden<<<G(NN*4),256,0,stream>>>(iptr, eid, L, m, dinv);
    k_gath<<<(NN+NB-1)/NB,256,0,stream>>>(buf0, ei, FP(2), iptr, eid, L, m, dinv,
                                          We16, FP(ICb[0]), bufA);
  }
  // ---- layer 2 (A = bufA, K=1024) ----
  {
    hipMemsetAsync(stats, 0, 2*HID*sizeof(float), stream);
    dim3 bg(200, 4);
    k_bnstats<u16><<<bg,256,0,stream>>>(bufA, stats, HID);
    k_bnfin<<<4,256,0,stream>>>(stats, FP(IG[1]), FP(IB[1]), scale, shift, HID);
    dim3 ft(HID/32, 64);
    k_foldT<<<ft,256,0,stream>>>(FP(IWg[1]), FP(ILw[1]), scale, Wt, HID, HID);
    k_cinit<<<8,256,0,stream>>>(FP(ILb[1]), cst);
    dim3 cg(32, HID/128);
    k_const<<<cg,256,0,stream>>>(FP(IWg[1]), FP(ILw[1]), shift, cst, HID);
    k_we16<<<40,256,0,stream>>>(FP(IWe[1]), We16);
    k_gemm<<<gg,512,0,stream>>>(bufA, HID, Wt, cst, buf0, bufB);
    k_sdot<<<G(NN*4),256,0,stream>>>(buf0, FP(IAttn[1]), ssrc, sdst);
    k_q<<<1,64,0,stream>>>(FP(IWe[1]), FP(IAttn[1]), qbuf);
    k_logits<<<G(EE*4),256,0,stream>>>(ei, FP(2), qbuf, FP(IAt[1]), ssrc, sdst, L);
    k_mden<<<G(NN*4),256,0,stream>>>(iptr, eid, L, m, dinv);
    k_gath<<<(NN+NB-1)/NB,256,0,stream>>>(buf0, ei, FP(2), iptr, eid, L, m, dinv,
                                          We16, FP(ICb[1]), bufB);
  }

  // ---- layer 3 (input = bufB) ----
  hipMemsetAsync(stats, 0, 2*HID*sizeof(float), stream);
  dim3 bg3(200, 4);
  k_bnstats<u16><<<bg3,256,0,stream>>>(bufB, stats, HID);
  k_bnfin<<<4,256,0,stream>>>(stats, FP(IG[2]), FP(IB[2]), scale, shift, HID);
  k_n3<<<NN,256,0,stream>>>(bufB, scale, shift, FP(IWg[2]), FP(ILw[2]), FP(ILb[2]),
                            FP(IAttn[2]), hg3, lin3, ssrc, sdst);
  k_logits3<<<G(EE),256,0,stream>>>(ei, FP(2), FP(IWe[2]), FP(IAttn[2]), FP(IAt[2]), ssrc, sdst, L);
  k_mden3<<<G(NN),256,0,stream>>>(iptr, eid, L, m, dinv);
  k_gather3<<<G(NN),256,0,stream>>>(ei, FP(2), iptr, eid, L, m, dinv, hg3,
                                    FP(IWe[2]), lin3, FP(ICb[2]), (float*)d_out);
}

// Round 4
// 980.648 us; speedup vs baseline: 1.0077x; 1.0077x over previous
//
#include <hip/hip_runtime.h>
#include <math.h>

#define NN 20000
#define EE 100000
#define FIN 167
#define KP1 256    // layer-1 K padded to mult of 64
#define HID 1024   // H*O = 4*256
#define OO 256
#define NB 16      // nodes per k_gath block

typedef unsigned short u16;
typedef short bf16x8 __attribute__((ext_vector_type(8)));
typedef float f32x4  __attribute__((ext_vector_type(4)));

__device__ __forceinline__ float bf(u16 u){ return __uint_as_float(((unsigned)u)<<16); }
__device__ __forceinline__ u16 fb(float v){            // f32 -> bf16 RNE
  unsigned u = __float_as_uint(v);
  return (u16)((u + 0x7FFFu + ((u>>16)&1u)) >> 16);
}
__device__ __forceinline__ float ldv(const float* p, long i){ return p[i]; }
__device__ __forceinline__ float ldv(const u16*   p, long i){ return bf(p[i]); }

// ---------------- CSR build ----------------
__global__ void k_count(const int* __restrict__ ei, int* __restrict__ counts){
  int e = blockIdx.x*256 + threadIdx.x;
  if (e < EE) atomicAdd(&counts[ei[EE+e]], 1);
}

__global__ __launch_bounds__(256) void k_scan(const int* __restrict__ counts, int* __restrict__ iptr){
  __shared__ int sd[256];
  int tid = threadIdx.x;
  int carry = 0;
  for (int base=0; base<NN; base+=256){
    int i = base+tid;
    int v = (i<NN)? counts[i] : 0;
    sd[tid]=v;
    __syncthreads();
    for (int off=1; off<256; off<<=1){
      int t = (tid>=off)? sd[tid-off] : 0;
      __syncthreads();
      sd[tid] += t;
      __syncthreads();
    }
    if (i<NN) iptr[i] = carry + sd[tid] - v;
    carry += sd[255];
    __syncthreads();
  }
  if (tid==0) iptr[NN]=carry;
}

__global__ void k_fill(const int* __restrict__ ei, const int* __restrict__ iptr,
                       int* __restrict__ cursor, int* __restrict__ eid){
  int e = blockIdx.x*256 + threadIdx.x;
  if (e < EE){
    int d = ei[EE+e];
    int pos = atomicAdd(&cursor[d],1);
    eid[iptr[d]+pos] = e;
  }
}

// ---------------- BatchNorm stats ----------------
template<typename T>
__global__ void k_bnstats(const T* __restrict__ X, float* __restrict__ sums, int F){
  int f = blockIdx.y*256 + threadIdx.x;
  if (f >= F) return;
  int r0 = blockIdx.x*100, r1 = r0+100;
  float s=0.f, s2=0.f;
  for (int r=r0;r<r1;r++){ float v = ldv(X,(long)r*F+f); s += v; s2 += v*v; }
  atomicAdd(&sums[f], s);
  atomicAdd(&sums[F+f], s2);
}

__global__ void k_bnfin(const float* __restrict__ sums, const float* __restrict__ g,
                        const float* __restrict__ b, float* __restrict__ scale,
                        float* __restrict__ shift, int F){
  int f = blockIdx.x*256 + threadIdx.x;
  if (f >= F) return;
  float mu  = sums[f]   * (1.f/NN);
  float var = sums[F+f] * (1.f/NN) - mu*mu;
  float sc  = rsqrtf(var + 1e-5f) * g[f];
  scale[f] = sc;
  shift[f] = b[f] - mu*sc;
}

// ---------------- BN-folded fused weight prep ----------------
__global__ __launch_bounds__(256) void k_foldT(const float* __restrict__ Wg, const float* __restrict__ Wl,
                        const float* __restrict__ scale,
                        u16* __restrict__ Wt, int K, int Kp){
  __shared__ float t[32][33];
  int k0 = blockIdx.x*32, c0 = blockIdx.y*32;
  int tx = threadIdx.x & 31, ty = threadIdx.x >> 5;
  bool second = (c0 >= HID);
  const float* W = second ? Wl : Wg;
  int cc0 = second ? c0 - HID : c0;
  #pragma unroll
  for (int i=0;i<4;i++){
    int k = k0 + ty + i*8;
    t[ty+i*8][tx] = (k < K) ? W[(long)k*HID + cc0 + tx] * scale[k] : 0.f;
  }
  __syncthreads();
  #pragma unroll
  for (int i=0;i<4;i++){
    int c = c0 + ty + i*8;
    Wt[(long)c*Kp + k0 + tx] = fb(t[tx][ty+i*8]);
  }
}

// cst init: lb for lin half, 0 for hg half
__global__ void k_cinit(const float* __restrict__ lb, float* __restrict__ cst){
  int c = blockIdx.x*256 + threadIdx.x;
  if (c < 2*HID) cst[c] = (c >= HID) ? lb[c-HID] : 0.f;
}

// cst[c] += sum_k shift[k]*W[k][c]  — parallel reduction, coalesced
__global__ __launch_bounds__(256) void k_const(const float* __restrict__ Wg, const float* __restrict__ Wl,
                        const float* __restrict__ shift, float* __restrict__ cst, int K){
  int tx = threadIdx.x & 63, ty = threadIdx.x >> 6;
  int c = blockIdx.x*64 + tx;
  bool second = c >= HID;
  const float* W = second ? Wl : Wg;
  int cc = second ? c-HID : c;
  int k0 = blockIdx.y*128;
  int k1 = min(K, k0+128);
  float s = 0.f;
  for (int k=k0+ty; k<k1; k+=4) s += shift[k]*W[(long)k*HID+cc];
  __shared__ float red[256];
  red[threadIdx.x] = s;
  __syncthreads();
  if (ty == 0){
    float tot = red[tx] + red[tx+64] + red[tx+128] + red[tx+192];
    atomicAdd(&cst[c], tot);
  }
}

__global__ void k_cast(const float* __restrict__ x, u16* __restrict__ xb){
  long idx = (long)blockIdx.x*256 + threadIdx.x;
  if (idx >= (long)NN*KP1) return;
  int n = (int)(idx / KP1), k = (int)(idx % KP1);
  xb[idx] = (k<FIN)? fb(x[(long)n*FIN+k]) : (u16)0;
}

__global__ void k_we16(const float* __restrict__ We, u16* __restrict__ We16){
  int i = blockIdx.x*256 + threadIdx.x;
  if (i < 10*HID) We16[i] = fb(We[i]);
}

// ---------------- MFMA GEMM v4: 256x128 tile, BK=64, k-chunk panels, counted-vmcnt ----------------
// De-risked counted-vmcnt pipeline: every parameter round 1 PROVED on this harness is kept
// (256x128 tile, 96 KB LDS, 512 thr, launch_bounds(512,2), grid 1264, raw fenced barriers,
// global_load_lds, XOR swizzle, same epilogue). Only the schedule changes.
//   Panels per K-tile (BK=64) split by k-chunk: Ak0|Ak1 (256r x 32k, 16 KB each),
//   Bk0|Bk1 (128r x 32k, 8 KB each); 48 KB/buffer x 2 buffers = 96 KB.
//   2 phases per tile; phase kk: {8x ds_read_b128 frags (kk) ; stage 3 panels of t+1 ;
//   16 MFMA ; s_waitcnt vmcnt(3) ; barrier}.  Ledger (in-order retirement, m135):
//     prologue: issue Ak0,Bk0,Ak1,Bk1(t0)=6 ; vmcnt(3) -> Ak0,Bk0 landed.
//     ph0 end: outstanding Ak1,Bk1(t)+Ak0,Bk0(t+1)=6 ; vmcnt(3) -> Ak1,Bk1(t) landed.
//     ph1 end: outstanding 6 of t+1 ; vmcnt(3) -> Ak0,Bk0(t+1) landed.  vmcnt(0) only last tile.
//   Cross-wave safety: every wave executes its vmcnt BEFORE the barrier; after the barrier all
//   slices of the guarded panels are in LDS.  No setprio / sched_barrier / inline lgkmcnt —
//   frag reads are compiler-visible LDS loads (compiler inserts lgkmcnt before MFMA use).
// Swizzle: rows of 32 u16 = 4 chunks of 16B; source chunk = c ^ (row&3); LDS linear;
// read at chunk position quad ^ (lo&3).  16 lanes -> 8 distinct bank slots = 2-way (free, m136).
#define MF(a_,b_,c_) __builtin_amdgcn_mfma_f32_16x16x32_bf16(a_,b_,c_,0,0,0)
#define FENCE asm volatile("" ::: "memory")
#define BAR do { FENCE; __builtin_amdgcn_s_barrier(); FENCE; } while(0)

__global__ __launch_bounds__(512,2) void k_gemm(const u16* __restrict__ A, int K,
                     const u16* __restrict__ Wt, const float* __restrict__ cst,
                     u16* __restrict__ Chg, u16* __restrict__ Clin){
  __shared__ u16 lds[2][24576];   // [buf][Ak0|Ak1|Bk0|Bk1] = 16K+16K+8K+8K bytes, total 96 KB
  int b = blockIdx.x;
  int wg = (b & 7)*158 + (b >> 3);          // 1264 % 8 == 0 -> bijective XCD swizzle
  int row0 = (wg >> 4)*256, col0 = (wg & 15)*128;
  int tid = threadIdx.x;
  int wave = tid >> 6, lane = tid & 63, quad = lane >> 4, lo = lane & 15;
  int wm = wave >> 1, wn = wave & 1;        // 4 M-waves x 2 N-waves, 64x64 out each
  // ---- staging source pointers (pre-swizzled global chunk) ----
  // A panel: 1024 chunks -> 2 slots/thread: slot s=i*512+tid, srow=s>>2, chunk=(s&3)^(srow&3)
  const u16* Apt[2];
  #pragma unroll
  for (int i=0;i<2;i++){
    int s = i*512 + tid, srow = s>>2;
    int gr = row0 + srow; if (gr >= NN) gr = NN-1;      // clamp: garbage rows never stored
    Apt[i] = A + (long)gr*K + (((s&3)^(srow&3))*8);
  }
  // B panel: 512 chunks -> 1 slot/thread
  int brow = tid>>2;
  const u16* Bpt = Wt + (long)(col0 + brow)*K + ((((tid&3)^(brow&3)))*8);
  // ---- ds_read fragment byte offsets within a buffer (same XOR) ----
  const char* ldsc = (const char*)&lds[0][0];
  int axor = lo & 3;
  int aoff = (wm*64 + lo)*64 + ((quad^axor)*16);            // A frag i at +i*1024 ; kk1 at +16384
  int boff = 32768 + (wn*64 + lo)*64 + ((quad^axor)*16);    // B frag n at +n*1024 ; kk1 at +8192
  int NT = K >> 6;
  f32x4 acc[4][4] = {};
  // ---- prologue: stage tile 0 into buf0, order Ak0,Bk0,Ak1,Bk1 ----
  {
    u16* d = (u16*)&lds[0][0];
    __builtin_amdgcn_global_load_lds(Apt[0],      d +          tid*8, 16, 0, 0);
    __builtin_amdgcn_global_load_lds(Apt[1],      d +  4096 +  tid*8, 16, 0, 0);
    __builtin_amdgcn_global_load_lds(Bpt,         d + 16384 +  tid*8, 16, 0, 0);
    __builtin_amdgcn_global_load_lds(Apt[0] + 32, d +  8192 +  tid*8, 16, 0, 0);
    __builtin_amdgcn_global_load_lds(Apt[1] + 32, d + 12288 +  tid*8, 16, 0, 0);
    __builtin_amdgcn_global_load_lds(Bpt    + 32, d + 20480 +  tid*8, 16, 0, 0);
    asm volatile("s_waitcnt vmcnt(3)" ::: "memory");   // Ak0,Bk0 landed; Ak1,Bk1 in flight
    BAR;
  }
  for (int t=0; t<NT; t++){
    const char* Lb = ldsc + (t&1)*49152;
    u16* Sb = (u16*)&lds[0][0] + ((t&1)^1)*24576;
    int k0n = (t+1) << 6;
    int nx = (t+1 < NT);
    bf16x8 af[4], bfr[4];
    // ======== phase 0 (kk=0): frags from Ak0,Bk0(t) ; stage Ak0,Bk0(t+1) ========
    #pragma unroll
    for (int i=0;i<4;i++) af[i]  = *(const bf16x8*)(Lb + aoff + i*1024);
    #pragma unroll
    for (int n=0;n<4;n++) bfr[n] = *(const bf16x8*)(Lb + boff + n*1024);
    if (nx){
      __builtin_amdgcn_global_load_lds(Apt[0] + k0n, Sb +          tid*8, 16, 0, 0);
      __builtin_amdgcn_global_load_lds(Apt[1] + k0n, Sb +  4096 +  tid*8, 16, 0, 0);
      __builtin_amdgcn_global_load_lds(Bpt    + k0n, Sb + 16384 +  tid*8, 16, 0, 0);
    }
    #pragma unroll
    for (int i=0;i<4;i++)
      #pragma unroll
      for (int n=0;n<4;n++)
        acc[i][n] = MF(af[i], bfr[n], acc[i][n]);
    if (nx) asm volatile("s_waitcnt vmcnt(3)" ::: "memory");  // Ak1,Bk1(t) landed
    else    asm volatile("s_waitcnt vmcnt(0)" ::: "memory");
    BAR;
    // ======== phase 1 (kk=1): frags from Ak1,Bk1(t) ; stage Ak1,Bk1(t+1) ========
    #pragma unroll
    for (int i=0;i<4;i++) af[i]  = *(const bf16x8*)(Lb + 16384 + aoff + i*1024);
    #pragma unroll
    for (int n=0;n<4;n++) bfr[n] = *(const bf16x8*)(Lb +  8192 + boff + n*1024);
    if (nx){
      __builtin_amdgcn_global_load_lds(Apt[0] + k0n + 32, Sb +  8192 +  tid*8, 16, 0, 0);
      __builtin_amdgcn_global_load_lds(Apt[1] + k0n + 32, Sb + 12288 +  tid*8, 16, 0, 0);
      __builtin_amdgcn_global_load_lds(Bpt    + k0n + 32, Sb + 20480 +  tid*8, 16, 0, 0);
    }
    #pragma unroll
    for (int i=0;i<4;i++)
      #pragma unroll
      for (int n=0;n<4;n++)
        acc[i][n] = MF(af[i], bfr[n], acc[i][n]);
    if (nx) asm volatile("s_waitcnt vmcnt(3)" ::: "memory");  // Ak0,Bk0(t+1) landed
    BAR;
  }
  // ---- epilogue (round-1 verified mapping) ----
  #pragma unroll
  for (int i=0;i<4;i++){
    #pragma unroll
    for (int n=0;n<4;n++){
      int col = col0 + wn*64 + n*16 + lo;
      float cs = cst[col];
      #pragma unroll
      for (int r=0;r<4;r++){
        int row = row0 + wm*64 + i*16 + quad*4 + r;   // C/D: col=lane&15, row=quad*4+reg
        if (row < NN){
          u16 o = fb(acc[i][n][r] + cs);
          if (col < HID) Chg[(long)row*HID + col] = o;
          else           Clin[(long)row*HID + col - HID] = o;
        }
      }
    }
  }
}
#undef MF
#undef BAR
#undef FENCE

// ---------------- per-(node,head) attention dots ----------------
__global__ void k_sdot(const u16* __restrict__ hg, const float* __restrict__ attn,
                       float* __restrict__ ssrc, float* __restrict__ sdst){
  int idx = blockIdx.x*256 + threadIdx.x;
  if (idx >= NN*4) return;
  int n = idx >> 2, h = idx & 3;
  const u16* hp = hg + (long)n*HID + h*OO;
  const float* a0 = attn + h*OO;
  const float* a1 = attn + HID + h*OO;
  float ss=0.f, sd=0.f;
  for (int d=0;d<OO;d++){ float v = bf(hp[d]); ss += v*a0[d]; sd += v*a1[d]; }
  ssrc[idx]=ss; sdst[idx]=sd;
}

__global__ void k_q(const float* __restrict__ We, const float* __restrict__ attn,
                    float* __restrict__ q){
  int t = threadIdx.x;
  if (t >= 40) return;
  int k = t >> 2, h = t & 3;
  float s = 0.f;
  for (int d=0; d<OO; d++) s += We[(long)k*HID + h*OO + d] * attn[2*HID + h*OO + d];
  q[k*4+h] = s;
}

__global__ void k_logits(const int* __restrict__ ei, const float* __restrict__ ea,
                         const float* __restrict__ q, const float* __restrict__ at,
                         const float* __restrict__ ssrc, const float* __restrict__ sdst,
                         float* __restrict__ L){
  int idx = blockIdx.x*256 + threadIdx.x;
  if (idx >= EE*4) return;
  int e = idx >> 2, h = idx & 3;
  int s = ei[e], dd = ei[EE+e];
  float se = 0.f;
  #pragma unroll
  for (int k=0;k<10;k++) se += ea[e*12+1+k] * q[k*4+h];
  float v = ssrc[s*4+h] + sdst[dd*4+h] + se + ea[e*12]*at[h];
  L[idx] = (v>0.f)? v : 0.2f*v;
}

__global__ void k_mden(const int* __restrict__ iptr, const int* __restrict__ eid,
                       const float* __restrict__ L, float* __restrict__ m, float* __restrict__ dinv){
  int idx = blockIdx.x*256 + threadIdx.x;
  if (idx >= NN*4) return;
  int n = idx >> 2, h = idx & 3;
  int b = iptr[n], e1 = iptr[n+1];
  float mx = -INFINITY;
  for (int i=b;i<e1;i++) mx = fmaxf(mx, L[eid[i]*4+h]);
  if (b == e1) mx = 0.f;
  float s = 0.f;
  for (int i=b;i<e1;i++) s += expf(L[eid[i]*4+h] - mx);
  m[idx] = mx;
  dinv[idx] = 1.f/(s + 1e-16f);
}

// ---------------- edge gather: NB nodes per block, We bf16 in LDS ----------------
__global__ __launch_bounds__(256) void k_gath(
    const u16* __restrict__ hg, const int* __restrict__ ei,
    const float* __restrict__ ea, const int* __restrict__ iptr,
    const int* __restrict__ eid, const float* __restrict__ L,
    const float* __restrict__ m, const float* __restrict__ dinv,
    const u16* __restrict__ We16, const float* __restrict__ cb,
    u16* __restrict__ lio)
{
  __shared__ u16  sWe[10*HID];   // 20 KB
  __shared__ float scb[HID];     // 4 KB
  int tid = threadIdx.x;
  for (int i=tid;i<10*HID;i+=256) sWe[i] = We16[i];
  for (int i=tid;i<HID;i+=256) scb[i] = cb[i];
  __syncthreads();
  int d0 = blockIdx.x*NB, dend = min(NN, d0+NB);
  for (int d=d0; d<dend; d++){
    float acc[4];
    #pragma unroll
    for (int j=0;j<4;j++) acc[j] = bf(lio[(long)d*HID + tid + j*256]);
    int b0 = iptr[d], en = iptr[d+1];
    float mm[4], dv[4];
    #pragma unroll
    for (int j=0;j<4;j++){ mm[j]=m[d*4+j]; dv[j]=dinv[d*4+j]; }
    for (int i=b0;i<en;i++){
      int e = eid[i], s_ = ei[e];
      float c10[10];
      #pragma unroll
      for (int k=0;k<10;k++) c10[k] = ea[e*12+1+k];
      float w4[4];
      #pragma unroll
      for (int j=0;j<4;j++) w4[j] = expf(L[e*4+j]-mm[j])*dv[j];
      const u16* hgs = hg + (long)s_*HID + tid;
      #pragma unroll
      for (int j=0;j<4;j++){
        int f = tid + j*256;
        float ew = 0.f;
        #pragma unroll
        for (int k=0;k<10;k++) ew += c10[k]*bf(sWe[k*HID+f]);
        acc[j] += w4[j]*(bf(hgs[j*256]) + ew);
      }
    }
    #pragma unroll
    for (int j=0;j<4;j++){
      int f = tid + j*256;
      lio[(long)d*HID+f] = fb(fmaxf(acc[j] + scb[f], 0.f));
    }
  }
}

// ---------------- layer 3 ----------------
__global__ __launch_bounds__(256) void k_n3(
    const u16* __restrict__ in, const float* __restrict__ scale, const float* __restrict__ shift,
    const float* __restrict__ Wg, const float* __restrict__ lw, const float* __restrict__ lb,
    const float* __restrict__ attn,
    float* __restrict__ hg3, float* __restrict__ lin3,
    float* __restrict__ ssrc, float* __restrict__ sdst)
{
  __shared__ float xin[1024];
  __shared__ float red[256];
  int n = blockIdx.x, tid = threadIdx.x;
  for (int k=tid;k<HID;k+=256) xin[k] = bf(in[(long)n*HID+k])*scale[k]+shift[k];
  __syncthreads();
  float p[4] = {0.f,0.f,0.f,0.f};
  for (int k=tid;k<HID;k+=256){
    float xv = xin[k];
    p[0] += xv*Wg[k*2];   p[1] += xv*Wg[k*2+1];
    p[2] += xv*lw[k*2];   p[3] += xv*lw[k*2+1];
  }
  float r[4];
  for (int q=0;q<4;q++){
    red[tid]=p[q]; __syncthreads();
    for (int o=128;o>0;o>>=1){ if(tid<o) red[tid]+=red[tid+o]; __syncthreads(); }
    r[q]=red[0]; __syncthreads();
  }
  if (tid==0){
    hg3[n*2]   = r[0];
    hg3[n*2+1] = r[1];
    lin3[n*2]   = r[2] + lb[0];
    lin3[n*2+1] = r[3] + lb[1];
    ssrc[n] = r[0]*attn[0] + r[1]*attn[1];
    sdst[n] = r[0]*attn[2] + r[1]*attn[3];
  }
}

__global__ void k_logits3(const int* __restrict__ ei, const float* __restrict__ ea,
                          const float* __restrict__ We, const float* __restrict__ attn,
                          const float* __restrict__ at, const float* __restrict__ ssrc,
                          const float* __restrict__ sdst, float* __restrict__ L){
  int e = blockIdx.x*256 + threadIdx.x;
  if (e >= EE) return;
  int s = ei[e], d = ei[EE+e];
  float e0=0.f, e1=0.f;
  #pragma unroll
  for (int k=0;k<10;k++){
    float c = ea[e*12+1+k];
    e0 += c*We[k*2]; e1 += c*We[k*2+1];
  }
  float se = e0*attn[4] + e1*attn[5];
  float v = ssrc[s] + sdst[d] + se + ea[e*12]*at[0];
  L[e] = (v>0.f)? v : 0.2f*v;
}

__global__ void k_mden3(const int* __restrict__ iptr, const int* __restrict__ eid,
                        const float* __restrict__ L, float* __restrict__ m, float* __restrict__ dinv){
  int n = blockIdx.x*256 + threadIdx.x;
  if (n >= NN) return;
  int b = iptr[n], e1 = iptr[n+1];
  float mx = -INFINITY;
  for (int i=b;i<e1;i++) mx = fmaxf(mx, L[eid[i]]);
  if (b == e1) mx = 0.f;
  float s = 0.f;
  for (int i=b;i<e1;i++) s += expf(L[eid[i]] - mx);
  m[n]=mx; dinv[n]=1.f/(s+1e-16f);
}

__global__ void k_gather3(const int* __restrict__ ei, const float* __restrict__ ea,
                          const int* __restrict__ iptr, const int* __restrict__ eid,
                          const float* __restrict__ L, const float* __restrict__ m,
                          const float* __restrict__ dinv, const float* __restrict__ hg3,
                          const float* __restrict__ We, const float* __restrict__ lin3,
                          const float* __restrict__ cb, float* __restrict__ out){
  int n = blockIdx.x*256 + threadIdx.x;
  if (n >= NN) return;
  int b = iptr[n], en = iptr[n+1];
  float a0=0.f, a1=0.f;
  float mn = m[n], dv = dinv[n];
  for (int i=b;i<en;i++){
    int e = eid[i], s_ = ei[e];
    float w = expf(L[e]-mn)*dv;
    float e0=0.f, e1v=0.f;
    #pragma unroll
    for (int k=0;k<10;k++){
      float c = ea[e*12+1+k];
      e0 += c*We[k*2]; e1v += c*We[k*2+1];
    }
    a0 += w*(hg3[s_*2]+e0);
    a1 += w*(hg3[s_*2+1]+e1v);
  }
  out[n*2]   = fmaxf(lin3[n*2]  +a0+cb[0], 0.f);
  out[n*2+1] = fmaxf(lin3[n*2+1]+a1+cb[1], 0.f);
}

extern "C" void kernel_launch(void* const* d_in, const int* in_sizes, int n_in,
                              void* d_out, int out_size, void* d_ws, size_t ws_size,
                              hipStream_t stream){
  const int* ei = (const int*)d_in[1];

  long long sz[64];
  {
    const long long* s64 = (const long long*)(const void*)in_sizes;
    bool is64 = (n_in >= 2) && (in_sizes[0] == 3340000) && (in_sizes[1] == 0)
                && (s64[1] == 200000);
    for (int i=0;i<n_in && i<64;i++) sz[i] = is64 ? s64[i] : (long long)in_sizes[i];
  }

  int IWg[3], IWe[3], IAttn[3], IAt[3], ICb[3], ILw[3], ILb[3], IG[3], IB[3];
  if (n_in > 8 && sz[8] == (long long)HID*HID){ // setup_inputs() dict order
    for (int l=0;l<3;l++){
      IWg[l]=3+l*5; IWe[l]=4+l*5; IAttn[l]=5+l*5; IAt[l]=6+l*5; ICb[l]=7+l*5;
      ILw[l]=18+l*4; ILb[l]=19+l*4; IG[l]=20+l*4; IB[l]=21+l*4;
    }
  } else {
    int idx=3;
    for (int l=0;l<3;l++){
      IWg[l]=idx++; IWe[l]=idx++; IAttn[l]=idx++; IAt[l]=idx++; ICb[l]=idx++;
      ILw[l]=idx++; ILb[l]=idx++; IG[l]=idx++; IB[l]=idx++;
    }
  }
  #define FP(i) ((const float*)d_in[(i)])

  char* ws = (char*)d_ws;
  size_t off = 0;
  auto alloc = [&](size_t bytes)->void*{ void* p = ws + off; off += (bytes + 255) & ~(size_t)255; return p; };
  auto G = [](long n){ return (int)((n+255)/256); };

  u16*   buf0 = (u16*)  alloc((size_t)NN*HID*2);   // hg (bf16)
  u16*   bufA = (u16*)  alloc((size_t)NN*HID*2);   // layer-1 lin/result
  u16*   bufB = (u16*)  alloc((size_t)NN*HID*2);   // layer-2 lin/result
  u16*   xbf  = (u16*)  alloc((size_t)NN*KP1*2);   // layer-1 A (bf16, padded)
  u16*   Wt   = (u16*)  alloc((size_t)2*HID*HID*2);// fused folded weights [2048][K] K-major
  u16*   We16 = (u16*)  alloc((size_t)10*HID*2);
  float* cst  = (float*)alloc(2*HID*4);
  float* L    = (float*)alloc((size_t)EE*4*4);
  float* m    = (float*)alloc((size_t)NN*4*4);
  float* dinv = (float*)alloc((size_t)NN*4*4);
  float* ssrc = (float*)alloc((size_t)NN*4*4);
  float* sdst = (float*)alloc((size_t)NN*4*4);
  int*   iptr = (int*)  alloc((size_t)(NN+4)*4);
  int*   cnts = (int*)  alloc((size_t)NN*4);
  int*   eid  = (int*)  alloc((size_t)EE*4);
  float* stats= (float*)alloc(2*HID*4);
  float* scale= (float*)alloc(HID*4);
  float* shift= (float*)alloc(HID*4);
  float* qbuf = (float*)alloc(64*4);
  float* hg3  = (float*)alloc((size_t)NN*2*4);
  float* lin3 = (float*)alloc((size_t)NN*2*4);

  // ---- CSR by dst ----
  hipMemsetAsync(cnts, 0, NN*sizeof(int), stream);
  k_count<<<G(EE),256,0,stream>>>(ei, cnts);
  k_scan<<<1,256,0,stream>>>(cnts, iptr);
  hipMemsetAsync(cnts, 0, NN*sizeof(int), stream);
  k_fill<<<G(EE),256,0,stream>>>(ei, iptr, cnts, eid);

  int gg = 1264;   // 79 row-tiles (256 rows) x 16 col-tiles (128 cols), XCD-swizzled in-kernel

  // ---- layer 1 (A = bf16(x), Kp=256) ----
  {
    hipMemsetAsync(stats, 0, 2*FIN*sizeof(float), stream);
    dim3 bg(200, 1);
    k_bnstats<float><<<bg,256,0,stream>>>(FP(0), stats, FIN);
    k_bnfin<<<1,256,0,stream>>>(stats, FP(IG[0]), FP(IB[0]), scale, shift, FIN);
    k_cast<<<G((long)NN*KP1),256,0,stream>>>(FP(0), xbf);
    dim3 ft(KP1/32, 64);
    k_foldT<<<ft,256,0,stream>>>(FP(IWg[0]), FP(ILw[0]), scale, Wt, FIN, KP1);
    k_cinit<<<8,256,0,stream>>>(FP(ILb[0]), cst);
    dim3 cg(32, (FIN+127)/128);
    k_const<<<cg,256,0,stream>>>(FP(IWg[0]), FP(ILw[0]), shift, cst, FIN);
    k_we16<<<40,256,0,stream>>>(FP(IWe[0]), We16);
    k_gemm<<<gg,512,0,stream>>>(xbf, KP1, Wt, cst, buf0, bufA);
    k_sdot<<<G(NN*4),256,0,stream>>>(buf0, FP(IAttn[0]), ssrc, sdst);
    k_q<<<1,64,0,stream>>>(FP(IWe[0]), FP(IAttn[0]), qbuf);
    k_logits<<<G(EE*4),256,0,stream>>>(ei, FP(2), qbuf, FP(IAt[0]), ssrc, sdst, L);
    k_mden<<<G(NN*4),256,0,stream>>>(iptr, eid, L, m, dinv);
    k_gath<<<(NN+NB-1)/NB,256,0,stream>>>(buf0, ei, FP(2), iptr, eid, L, m, dinv,
                                          We16, FP(ICb[0]), bufA);
  }
  // ---- layer 2 (A = bufA, K=1024) ----
  {
    hipMemsetAsync(stats, 0, 2*HID*sizeof(float), stream);
    dim3 bg(200, 4);
    k_bnstats<u16><<<bg,256,0,stream>>>(bufA, stats, HID);
    k_bnfin<<<4,256,0,stream>>>(stats, FP(IG[1]), FP(IB[1]), scale, shift, HID);
    dim3 ft(HID/32, 64);
    k_foldT<<<ft,256,0,stream>>>(FP(IWg[1]), FP(ILw[1]), scale, Wt, HID, HID);
    k_cinit<<<8,256,0,stream>>>(FP(ILb[1]), cst);
    dim3 cg(32, HID/128);
    k_const<<<cg,256,0,stream>>>(FP(IWg[1]), FP(ILw[1]), shift, cst, HID);
    k_we16<<<40,256,0,stream>>>(FP(IWe[1]), We16);
    k_gemm<<<gg,512,0,stream>>>(bufA, HID, Wt, cst, buf0, bufB);
    k_sdot<<<G(NN*4),256,0,stream>>>(buf0, FP(IAttn[1]), ssrc, sdst);
    k_q<<<1,64,0,stream>>>(FP(IWe[1]), FP(IAttn[1]), qbuf);
    k_logits<<<G(EE*4),256,0,stream>>>(ei, FP(2), qbuf, FP(IAt[1]), ssrc, sdst, L);
    k_mden<<<G(NN*4),256,0,stream>>>(iptr, eid, L, m, dinv);
    k_gath<<<(NN+NB-1)/NB,256,0,stream>>>(buf0, ei, FP(2), iptr, eid, L, m, dinv,
                                          We16, FP(ICb[1]), bufB);
  }

  // ---- layer 3 (input = bufB) ----
  hipMemsetAsync(stats, 0, 2*HID*sizeof(float), stream);
  dim3 bg3(200, 4);
  k_bnstats<u16><<<bg3,256,0,stream>>>(bufB, stats, HID);
  k_bnfin<<<4,256,0,stream>>>(stats, FP(IG[2]), FP(IB[2]), scale, shift, HID);
  k_n3<<<NN,256,0,stream>>>(bufB, scale, shift, FP(IWg[2]), FP(ILw[2]), FP(ILb[2]),
                            FP(IAttn[2]), hg3, lin3, ssrc, sdst);
  k_logits3<<<G(EE),256,0,stream>>>(ei, FP(2), FP(IWe[2]), FP(IAttn[2]), FP(IAt[2]), ssrc, sdst, L);
  k_mden3<<<G(NN),256,0,stream>>>(iptr, eid, L, m, dinv);
  k_gather3<<<G(NN),256,0,stream>>>(ei, FP(2), iptr, eid, L, m, dinv, hg3,
                                    FP(IWe[2]), lin3, FP(ICb[2]), (float*)d_out);
}

// Round 5
// 912.539 us; speedup vs baseline: 1.0829x; 1.0746x over previous
//
#include <hip/hip_runtime.h>
#include <math.h>

#define NN 20000
#define EE 100000
#define FIN 167
#define KP1 256    // layer-1 K padded to mult of 64
#define HID 1024   // H*O = 4*256
#define OO 256
#define NB 16      // nodes per k_gath block

typedef unsigned short u16;
typedef short bf16x8 __attribute__((ext_vector_type(8)));
typedef short s16x4  __attribute__((ext_vector_type(4)));
typedef float f32x4  __attribute__((ext_vector_type(4)));

__device__ __forceinline__ float bf(u16 u){ return __uint_as_float(((unsigned)u)<<16); }
__device__ __forceinline__ u16 fb(float v){            // f32 -> bf16 RNE
  unsigned u = __float_as_uint(v);
  return (u16)((u + 0x7FFFu + ((u>>16)&1u)) >> 16);
}
__device__ __forceinline__ float ldv(const float* p, long i){ return p[i]; }
__device__ __forceinline__ float ldv(const u16*   p, long i){ return bf(p[i]); }

// ---------------- CSR build ----------------
__global__ void k_count(const int* __restrict__ ei, int* __restrict__ counts){
  int e = blockIdx.x*256 + threadIdx.x;
  if (e < EE) atomicAdd(&counts[ei[EE+e]], 1);
}

__global__ __launch_bounds__(256) void k_scan(const int* __restrict__ counts, int* __restrict__ iptr){
  __shared__ int sd[256];
  int tid = threadIdx.x;
  int carry = 0;
  for (int base=0; base<NN; base+=256){
    int i = base+tid;
    int v = (i<NN)? counts[i] : 0;
    sd[tid]=v;
    __syncthreads();
    for (int off=1; off<256; off<<=1){
      int t = (tid>=off)? sd[tid-off] : 0;
      __syncthreads();
      sd[tid] += t;
      __syncthreads();
    }
    if (i<NN) iptr[i] = carry + sd[tid] - v;
    carry += sd[255];
    __syncthreads();
  }
  if (tid==0) iptr[NN]=carry;
}

__global__ void k_fill(const int* __restrict__ ei, const int* __restrict__ iptr,
                       int* __restrict__ cursor, int* __restrict__ eid){
  int e = blockIdx.x*256 + threadIdx.x;
  if (e < EE){
    int d = ei[EE+e];
    int pos = atomicAdd(&cursor[d],1);
    eid[iptr[d]+pos] = e;
  }
}

// ---------------- BatchNorm stats ----------------
template<typename T>
__global__ void k_bnstats(const T* __restrict__ X, float* __restrict__ sums, int F){
  int f = blockIdx.y*256 + threadIdx.x;
  if (f >= F) return;
  int r0 = blockIdx.x*100, r1 = r0+100;
  float s=0.f, s2=0.f;
  for (int r=r0;r<r1;r++){ float v = ldv(X,(long)r*F+f); s += v; s2 += v*v; }
  atomicAdd(&sums[f], s);
  atomicAdd(&sums[F+f], s2);
}

__global__ void k_bnfin(const float* __restrict__ sums, const float* __restrict__ g,
                        const float* __restrict__ b, float* __restrict__ scale,
                        float* __restrict__ shift, int F){
  int f = blockIdx.x*256 + threadIdx.x;
  if (f >= F) return;
  float mu  = sums[f]   * (1.f/NN);
  float var = sums[F+f] * (1.f/NN) - mu*mu;
  float sc  = rsqrtf(var + 1e-5f) * g[f];
  scale[f] = sc;
  shift[f] = b[f] - mu*sc;
}

// ---------------- BN-folded fused weight prep ----------------
__global__ __launch_bounds__(256) void k_foldT(const float* __restrict__ Wg, const float* __restrict__ Wl,
                        const float* __restrict__ scale,
                        u16* __restrict__ Wt, int K, int Kp){
  __shared__ float t[32][33];
  int k0 = blockIdx.x*32, c0 = blockIdx.y*32;
  int tx = threadIdx.x & 31, ty = threadIdx.x >> 5;
  bool second = (c0 >= HID);
  const float* W = second ? Wl : Wg;
  int cc0 = second ? c0 - HID : c0;
  #pragma unroll
  for (int i=0;i<4;i++){
    int k = k0 + ty + i*8;
    t[ty+i*8][tx] = (k < K) ? W[(long)k*HID + cc0 + tx] * scale[k] : 0.f;
  }
  __syncthreads();
  #pragma unroll
  for (int i=0;i<4;i++){
    int c = c0 + ty + i*8;
    Wt[(long)c*Kp + k0 + tx] = fb(t[tx][ty+i*8]);
  }
}

// cst init: lb for lin half, 0 for hg half
__global__ void k_cinit(const float* __restrict__ lb, float* __restrict__ cst){
  int c = blockIdx.x*256 + threadIdx.x;
  if (c < 2*HID) cst[c] = (c >= HID) ? lb[c-HID] : 0.f;
}

// cst[c] += sum_k shift[k]*W[k][c]  — parallel reduction, coalesced
__global__ __launch_bounds__(256) void k_const(const float* __restrict__ Wg, const float* __restrict__ Wl,
                        const float* __restrict__ shift, float* __restrict__ cst, int K){
  int tx = threadIdx.x & 63, ty = threadIdx.x >> 6;
  int c = blockIdx.x*64 + tx;
  bool second = c >= HID;
  const float* W = second ? Wl : Wg;
  int cc = second ? c-HID : c;
  int k0 = blockIdx.y*128;
  int k1 = min(K, k0+128);
  float s = 0.f;
  for (int k=k0+ty; k<k1; k+=4) s += shift[k]*W[(long)k*HID+cc];
  __shared__ float red[256];
  red[threadIdx.x] = s;
  __syncthreads();
  if (ty == 0){
    float tot = red[tx] + red[tx+64] + red[tx+128] + red[tx+192];
    atomicAdd(&cst[c], tot);
  }
}

__global__ void k_cast(const float* __restrict__ x, u16* __restrict__ xb){
  long idx = (long)blockIdx.x*256 + threadIdx.x;
  if (idx >= (long)NN*KP1) return;
  int n = (int)(idx / KP1), k = (int)(idx % KP1);
  xb[idx] = (k<FIN)? fb(x[(long)n*FIN+k]) : (u16)0;
}

__global__ void k_we16(const float* __restrict__ We, u16* __restrict__ We16){
  int i = blockIdx.x*256 + threadIdx.x;
  if (i < 10*HID) We16[i] = fb(We[i]);
}

// ---------------- MFMA GEMM (round-4 verified, unchanged) ----------------
#define MF(a_,b_,c_) __builtin_amdgcn_mfma_f32_16x16x32_bf16(a_,b_,c_,0,0,0)
#define FENCE asm volatile("" ::: "memory")
#define BAR do { FENCE; __builtin_amdgcn_s_barrier(); FENCE; } while(0)

__global__ __launch_bounds__(512,2) void k_gemm(const u16* __restrict__ A, int K,
                     const u16* __restrict__ Wt, const float* __restrict__ cst,
                     u16* __restrict__ Chg, u16* __restrict__ Clin){
  __shared__ u16 lds[2][24576];   // [buf][Ak0|Ak1|Bk0|Bk1] = 16K+16K+8K+8K bytes, total 96 KB
  int b = blockIdx.x;
  int wg = (b & 7)*158 + (b >> 3);          // 1264 % 8 == 0 -> bijective XCD swizzle
  int row0 = (wg >> 4)*256, col0 = (wg & 15)*128;
  int tid = threadIdx.x;
  int wave = tid >> 6, lane = tid & 63, quad = lane >> 4, lo = lane & 15;
  int wm = wave >> 1, wn = wave & 1;        // 4 M-waves x 2 N-waves, 64x64 out each
  const u16* Apt[2];
  #pragma unroll
  for (int i=0;i<2;i++){
    int s = i*512 + tid, srow = s>>2;
    int gr = row0 + srow; if (gr >= NN) gr = NN-1;      // clamp: garbage rows never stored
    Apt[i] = A + (long)gr*K + (((s&3)^(srow&3))*8);
  }
  int brow = tid>>2;
  const u16* Bpt = Wt + (long)(col0 + brow)*K + ((((tid&3)^(brow&3)))*8);
  const char* ldsc = (const char*)&lds[0][0];
  int axor = lo & 3;
  int aoff = (wm*64 + lo)*64 + ((quad^axor)*16);
  int boff = 32768 + (wn*64 + lo)*64 + ((quad^axor)*16);
  int NT = K >> 6;
  f32x4 acc[4][4] = {};
  {
    u16* d = (u16*)&lds[0][0];
    __builtin_amdgcn_global_load_lds(Apt[0],      d +          tid*8, 16, 0, 0);
    __builtin_amdgcn_global_load_lds(Apt[1],      d +  4096 +  tid*8, 16, 0, 0);
    __builtin_amdgcn_global_load_lds(Bpt,         d + 16384 +  tid*8, 16, 0, 0);
    __builtin_amdgcn_global_load_lds(Apt[0] + 32, d +  8192 +  tid*8, 16, 0, 0);
    __builtin_amdgcn_global_load_lds(Apt[1] + 32, d + 12288 +  tid*8, 16, 0, 0);
    __builtin_amdgcn_global_load_lds(Bpt    + 32, d + 20480 +  tid*8, 16, 0, 0);
    asm volatile("s_waitcnt vmcnt(3)" ::: "memory");
    BAR;
  }
  for (int t=0; t<NT; t++){
    const char* Lb = ldsc + (t&1)*49152;
    u16* Sb = (u16*)&lds[0][0] + ((t&1)^1)*24576;
    int k0n = (t+1) << 6;
    int nx = (t+1 < NT);
    bf16x8 af[4], bfr[4];
    #pragma unroll
    for (int i=0;i<4;i++) af[i]  = *(const bf16x8*)(Lb + aoff + i*1024);
    #pragma unroll
    for (int n=0;n<4;n++) bfr[n] = *(const bf16x8*)(Lb + boff + n*1024);
    if (nx){
      __builtin_amdgcn_global_load_lds(Apt[0] + k0n, Sb +          tid*8, 16, 0, 0);
      __builtin_amdgcn_global_load_lds(Apt[1] + k0n, Sb +  4096 +  tid*8, 16, 0, 0);
      __builtin_amdgcn_global_load_lds(Bpt    + k0n, Sb + 16384 +  tid*8, 16, 0, 0);
    }
    #pragma unroll
    for (int i=0;i<4;i++)
      #pragma unroll
      for (int n=0;n<4;n++)
        acc[i][n] = MF(af[i], bfr[n], acc[i][n]);
    if (nx) asm volatile("s_waitcnt vmcnt(3)" ::: "memory");
    else    asm volatile("s_waitcnt vmcnt(0)" ::: "memory");
    BAR;
    #pragma unroll
    for (int i=0;i<4;i++) af[i]  = *(const bf16x8*)(Lb + 16384 + aoff + i*1024);
    #pragma unroll
    for (int n=0;n<4;n++) bfr[n] = *(const bf16x8*)(Lb +  8192 + boff + n*1024);
    if (nx){
      __builtin_amdgcn_global_load_lds(Apt[0] + k0n + 32, Sb +  8192 +  tid*8, 16, 0, 0);
      __builtin_amdgcn_global_load_lds(Apt[1] + k0n + 32, Sb + 12288 +  tid*8, 16, 0, 0);
      __builtin_amdgcn_global_load_lds(Bpt    + k0n + 32, Sb + 20480 +  tid*8, 16, 0, 0);
    }
    #pragma unroll
    for (int i=0;i<4;i++)
      #pragma unroll
      for (int n=0;n<4;n++)
        acc[i][n] = MF(af[i], bfr[n], acc[i][n]);
    if (nx) asm volatile("s_waitcnt vmcnt(3)" ::: "memory");
    BAR;
  }
  #pragma unroll
  for (int i=0;i<4;i++){
    #pragma unroll
    for (int n=0;n<4;n++){
      int col = col0 + wn*64 + n*16 + lo;
      float cs = cst[col];
      #pragma unroll
      for (int r=0;r<4;r++){
        int row = row0 + wm*64 + i*16 + quad*4 + r;   // C/D: col=lane&15, row=quad*4+reg
        if (row < NN){
          u16 o = fb(acc[i][n][r] + cs);
          if (col < HID) Chg[(long)row*HID + col] = o;
          else           Clin[(long)row*HID + col - HID] = o;
        }
      }
    }
  }
}
#undef MF
#undef BAR
#undef FENCE

// ---------------- per-(node,head) attention dots: wave-parallel, coalesced ----------------
__global__ __launch_bounds__(256) void k_sdot(const u16* __restrict__ hg, const float* __restrict__ attn,
                       float* __restrict__ ssrc, float* __restrict__ sdst){
  int unit = blockIdx.x*4 + (threadIdx.x >> 6);   // one wave per (n,h)
  if (unit >= NN*4) return;
  int lane = threadIdx.x & 63;
  int n = unit >> 2, h = unit & 3;
  const u16* hp = hg + (long)n*HID + h*OO + lane*4;
  s16x4 v = *(const s16x4*)hp;
  float4 x0 = *(const float4*)(attn + h*OO + lane*4);
  float4 x1 = *(const float4*)(attn + HID + h*OO + lane*4);
  float f0 = bf((u16)v.x), f1 = bf((u16)v.y), f2 = bf((u16)v.z), f3 = bf((u16)v.w);
  float ss = f0*x0.x + f1*x0.y + f2*x0.z + f3*x0.w;
  float sd = f0*x1.x + f1*x1.y + f2*x1.z + f3*x1.w;
  #pragma unroll
  for (int off=32; off>0; off>>=1){
    ss += __shfl_down(ss, off);
    sd += __shfl_down(sd, off);
  }
  if (lane==0){ ssrc[unit]=ss; sdst[unit]=sd; }
}

__global__ void k_q(const float* __restrict__ We, const float* __restrict__ attn,
                    float* __restrict__ q){
  int t = threadIdx.x;
  if (t >= 40) return;
  int k = t >> 2, h = t & 3;
  float s = 0.f;
  for (int d=0; d<OO; d++) s += We[(long)k*HID + h*OO + d] * attn[2*HID + h*OO + d];
  q[k*4+h] = s;
}

__global__ void k_logits(const int* __restrict__ ei, const float* __restrict__ ea,
                         const float* __restrict__ q, const float* __restrict__ at,
                         const float* __restrict__ ssrc, const float* __restrict__ sdst,
                         float* __restrict__ L){
  int idx = blockIdx.x*256 + threadIdx.x;
  if (idx >= EE*4) return;
  int e = idx >> 2, h = idx & 3;
  int s = ei[e], dd = ei[EE+e];
  float se = 0.f;
  #pragma unroll
  for (int k=0;k<10;k++) se += ea[e*12+1+k] * q[k*4+h];
  float v = ssrc[s*4+h] + sdst[dd*4+h] + se + ea[e*12]*at[h];
  L[idx] = (v>0.f)? v : 0.2f*v;
}

// softmax finalize: writes w = exp(L-m)*dinv IN PLACE into L, and accumulates
// cw[n][h][k] = sum_e w * ea[e][1+k]  (factored edge-feature weights)
__global__ void k_mden(const int* __restrict__ iptr, const int* __restrict__ eid,
                       const float* __restrict__ ea, float* __restrict__ L,
                       float* __restrict__ cw){
  int idx = blockIdx.x*256 + threadIdx.x;
  if (idx >= NN*4) return;
  int n = idx >> 2, h = idx & 3;
  int b = iptr[n], e1 = iptr[n+1];
  float mx = -INFINITY;
  for (int i=b;i<e1;i++) mx = fmaxf(mx, L[eid[i]*4+h]);
  if (b == e1) mx = 0.f;
  float s = 0.f;
  for (int i=b;i<e1;i++) s += expf(L[eid[i]*4+h] - mx);
  float dv = 1.f/(s + 1e-16f);
  float c[10] = {0.f,0.f,0.f,0.f,0.f,0.f,0.f,0.f,0.f,0.f};
  for (int i=b;i<e1;i++){
    int e = eid[i];
    float w = expf(L[e*4+h]-mx)*dv;
    L[e*4+h] = w;                       // safe: only this thread touches (e,h)
    #pragma unroll
    for (int k=0;k<10;k++) c[k] += w*ea[e*12+1+k];
  }
  float* cp = cw + (long)idx*10;
  #pragma unroll
  for (int k=0;k<10;k++) cp[k] = c[k];
}

// ---------------- edge gather v2: pure h[src] gather + per-node factored ew ----------------
__global__ __launch_bounds__(256) void k_gath(
    const u16* __restrict__ hg, const int* __restrict__ ei,
    const int* __restrict__ iptr, const int* __restrict__ eid,
    const float* __restrict__ L,      // holds w[e][h] (from k_mden)
    const float* __restrict__ cw,     // [NN][4][10]
    const u16* __restrict__ We16, const float* __restrict__ cb,
    u16* __restrict__ lio)
{
  __shared__ u16  sWe[10*HID];   // 20 KB
  __shared__ float scb[HID];     // 4 KB
  int tid = threadIdx.x;
  for (int i=tid;i<10*HID;i+=256) sWe[i] = We16[i];
  for (int i=tid;i<HID;i+=256) scb[i] = cb[i];
  __syncthreads();
  int d0 = blockIdx.x*NB, dend = min(NN, d0+NB);
  for (int d=d0; d<dend; d++){
    float acc[4];
    #pragma unroll
    for (int j=0;j<4;j++) acc[j] = bf(lio[(long)d*HID + tid + j*256]);
    int b0 = iptr[d], en = iptr[d+1];
    for (int i=b0;i<en;i++){
      int e = eid[i], s_ = ei[e];
      float4 w4 = *(const float4*)(L + (long)e*4);   // broadcast
      const u16* hgs = hg + (long)s_*HID + tid;
      acc[0] += w4.x*bf(hgs[0]);
      acc[1] += w4.y*bf(hgs[256]);
      acc[2] += w4.z*bf(hgs[512]);
      acc[3] += w4.w*bf(hgs[768]);
    }
    const float* cp = cw + (long)d*40;
    #pragma unroll
    for (int j=0;j<4;j++){
      float ew = 0.f;
      #pragma unroll
      for (int k=0;k<10;k++) ew += cp[j*10+k]*bf(sWe[k*HID + tid + j*256]);
      acc[j] += ew;
    }
    #pragma unroll
    for (int j=0;j<4;j++){
      int f = tid + j*256;
      lio[(long)d*HID+f] = fb(fmaxf(acc[j] + scb[f], 0.f));
    }
  }
}

// ---------------- layer 3 ----------------
__global__ __launch_bounds__(256) void k_n3(
    const u16* __restrict__ in, const float* __restrict__ scale, const float* __restrict__ shift,
    const float* __restrict__ Wg, const float* __restrict__ lw, const float* __restrict__ lb,
    const float* __restrict__ attn,
    float* __restrict__ hg3, float* __restrict__ lin3,
    float* __restrict__ ssrc, float* __restrict__ sdst)
{
  __shared__ float xin[1024];
  __shared__ float red[256];
  int n = blockIdx.x, tid = threadIdx.x;
  for (int k=tid;k<HID;k+=256) xin[k] = bf(in[(long)n*HID+k])*scale[k]+shift[k];
  __syncthreads();
  float p[4] = {0.f,0.f,0.f,0.f};
  for (int k=tid;k<HID;k+=256){
    float xv = xin[k];
    p[0] += xv*Wg[k*2];   p[1] += xv*Wg[k*2+1];
    p[2] += xv*lw[k*2];   p[3] += xv*lw[k*2+1];
  }
  float r[4];
  for (int q=0;q<4;q++){
    red[tid]=p[q]; __syncthreads();
    for (int o=128;o>0;o>>=1){ if(tid<o) red[tid]+=red[tid+o]; __syncthreads(); }
    r[q]=red[0]; __syncthreads();
  }
  if (tid==0){
    hg3[n*2]   = r[0];
    hg3[n*2+1] = r[1];
    lin3[n*2]   = r[2] + lb[0];
    lin3[n*2+1] = r[3] + lb[1];
    ssrc[n] = r[0]*attn[0] + r[1]*attn[1];
    sdst[n] = r[0]*attn[2] + r[1]*attn[3];
  }
}

__global__ void k_logits3(const int* __restrict__ ei, const float* __restrict__ ea,
                          const float* __restrict__ We, const float* __restrict__ attn,
                          const float* __restrict__ at, const float* __restrict__ ssrc,
                          const float* __restrict__ sdst, float* __restrict__ L){
  int e = blockIdx.x*256 + threadIdx.x;
  if (e >= EE) return;
  int s = ei[e], d = ei[EE+e];
  float e0=0.f, e1=0.f;
  #pragma unroll
  for (int k=0;k<10;k++){
    float c = ea[e*12+1+k];
    e0 += c*We[k*2]; e1 += c*We[k*2+1];
  }
  float se = e0*attn[4] + e1*attn[5];
  float v = ssrc[s] + sdst[d] + se + ea[e*12]*at[0];
  L[e] = (v>0.f)? v : 0.2f*v;
}

// layer-3 softmax finalize: w in place + cw3[n][k]
__global__ void k_mden3(const int* __restrict__ iptr, const int* __restrict__ eid,
                        const float* __restrict__ ea, float* __restrict__ L,
                        float* __restrict__ cw){
  int n = blockIdx.x*256 + threadIdx.x;
  if (n >= NN) return;
  int b = iptr[n], e1 = iptr[n+1];
  float mx = -INFINITY;
  for (int i=b;i<e1;i++) mx = fmaxf(mx, L[eid[i]]);
  if (b == e1) mx = 0.f;
  float s = 0.f;
  for (int i=b;i<e1;i++) s += expf(L[eid[i]] - mx);
  float dv = 1.f/(s+1e-16f);
  float c[10] = {0.f,0.f,0.f,0.f,0.f,0.f,0.f,0.f,0.f,0.f};
  for (int i=b;i<e1;i++){
    int e = eid[i];
    float w = expf(L[e]-mx)*dv;
    L[e] = w;
    #pragma unroll
    for (int k=0;k<10;k++) c[k] += w*ea[e*12+1+k];
  }
  float* cp = cw + (long)n*10;
  #pragma unroll
  for (int k=0;k<10;k++) cp[k] = c[k];
}

__global__ void k_gather3(const int* __restrict__ ei,
                          const int* __restrict__ iptr, const int* __restrict__ eid,
                          const float* __restrict__ L,      // holds w[e]
                          const float* __restrict__ cw,     // [NN][10]
                          const float* __restrict__ hg3,
                          const float* __restrict__ We, const float* __restrict__ lin3,
                          const float* __restrict__ cb, float* __restrict__ out){
  int n = blockIdx.x*256 + threadIdx.x;
  if (n >= NN) return;
  int b = iptr[n], en = iptr[n+1];
  const float* cp = cw + (long)n*10;
  float e0f=0.f, e1f=0.f;
  #pragma unroll
  for (int k=0;k<10;k++){ e0f += cp[k]*We[k*2]; e1f += cp[k]*We[k*2+1]; }
  float a0=0.f, a1=0.f;
  for (int i=b;i<en;i++){
    int e = eid[i], s_ = ei[e];
    float w = L[e];
    a0 += w*hg3[s_*2];
    a1 += w*hg3[s_*2+1];
  }
  out[n*2]   = fmaxf(lin3[n*2]  +a0+e0f+cb[0], 0.f);
  out[n*2+1] = fmaxf(lin3[n*2+1]+a1+e1f+cb[1], 0.f);
}

extern "C" void kernel_launch(void* const* d_in, const int* in_sizes, int n_in,
                              void* d_out, int out_size, void* d_ws, size_t ws_size,
                              hipStream_t stream){
  const int* ei = (const int*)d_in[1];

  long long sz[64];
  {
    const long long* s64 = (const long long*)(const void*)in_sizes;
    bool is64 = (n_in >= 2) && (in_sizes[0] == 3340000) && (in_sizes[1] == 0)
                && (s64[1] == 200000);
    for (int i=0;i<n_in && i<64;i++) sz[i] = is64 ? s64[i] : (long long)in_sizes[i];
  }

  int IWg[3], IWe[3], IAttn[3], IAt[3], ICb[3], ILw[3], ILb[3], IG[3], IB[3];
  if (n_in > 8 && sz[8] == (long long)HID*HID){ // setup_inputs() dict order
    for (int l=0;l<3;l++){
      IWg[l]=3+l*5; IWe[l]=4+l*5; IAttn[l]=5+l*5; IAt[l]=6+l*5; ICb[l]=7+l*5;
      ILw[l]=18+l*4; ILb[l]=19+l*4; IG[l]=20+l*4; IB[l]=21+l*4;
    }
  } else {
    int idx=3;
    for (int l=0;l<3;l++){
      IWg[l]=idx++; IWe[l]=idx++; IAttn[l]=idx++; IAt[l]=idx++; ICb[l]=idx++;
      ILw[l]=idx++; ILb[l]=idx++; IG[l]=idx++; IB[l]=idx++;
    }
  }
  #define FP(i) ((const float*)d_in[(i)])

  char* ws = (char*)d_ws;
  size_t off = 0;
  auto alloc = [&](size_t bytes)->void*{ void* p = ws + off; off += (bytes + 255) & ~(size_t)255; return p; };
  auto G = [](long n){ return (int)((n+255)/256); };

  u16*   buf0 = (u16*)  alloc((size_t)NN*HID*2);   // hg (bf16)
  u16*   bufA = (u16*)  alloc((size_t)NN*HID*2);   // layer-1 lin/result
  u16*   bufB = (u16*)  alloc((size_t)NN*HID*2);   // layer-2 lin/result
  u16*   xbf  = (u16*)  alloc((size_t)NN*KP1*2);   // layer-1 A (bf16, padded)
  u16*   Wt   = (u16*)  alloc((size_t)2*HID*HID*2);// fused folded weights [2048][K] K-major
  u16*   We16 = (u16*)  alloc((size_t)10*HID*2);
  float* cst  = (float*)alloc(2*HID*4);
  float* L    = (float*)alloc((size_t)EE*4*4);
  float* m    = (float*)alloc((size_t)NN*4*4);
  float* dinv = (float*)alloc((size_t)NN*4*4);
  float* ssrc = (float*)alloc((size_t)NN*4*4);
  float* sdst = (float*)alloc((size_t)NN*4*4);
  int*   iptr = (int*)  alloc((size_t)(NN+4)*4);
  int*   cnts = (int*)  alloc((size_t)NN*4);
  int*   eid  = (int*)  alloc((size_t)EE*4);
  float* stats= (float*)alloc(2*HID*4);
  float* scale= (float*)alloc(HID*4);
  float* shift= (float*)alloc(HID*4);
  float* qbuf = (float*)alloc(64*4);
  float* hg3  = (float*)alloc((size_t)NN*2*4);
  float* lin3 = (float*)alloc((size_t)NN*2*4);
  float* cw   = (float*)alloc((size_t)NN*40*4);    // factored edge-feature weights

  // ---- CSR by dst ----
  hipMemsetAsync(cnts, 0, NN*sizeof(int), stream);
  k_count<<<G(EE),256,0,stream>>>(ei, cnts);
  k_scan<<<1,256,0,stream>>>(cnts, iptr);
  hipMemsetAsync(cnts, 0, NN*sizeof(int), stream);
  k_fill<<<G(EE),256,0,stream>>>(ei, iptr, cnts, eid);

  int gg = 1264;   // 79 row-tiles (256 rows) x 16 col-tiles (128 cols), XCD-swizzled in-kernel
  int gsd = (NN*4+3)/4;   // k_sdot: one wave per (n,h)

  // ---- layer 1 (A = bf16(x), Kp=256) ----
  {
    hipMemsetAsync(stats, 0, 2*FIN*sizeof(float), stream);
    dim3 bg(200, 1);
    k_bnstats<float><<<bg,256,0,stream>>>(FP(0), stats, FIN);
    k_bnfin<<<1,256,0,stream>>>(stats, FP(IG[0]), FP(IB[0]), scale, shift, FIN);
    k_cast<<<G((long)NN*KP1),256,0,stream>>>(FP(0), xbf);
    dim3 ft(KP1/32, 64);
    k_foldT<<<ft,256,0,stream>>>(FP(IWg[0]), FP(ILw[0]), scale, Wt, FIN, KP1);
    k_cinit<<<8,256,0,stream>>>(FP(ILb[0]), cst);
    dim3 cg(32, (FIN+127)/128);
    k_const<<<cg,256,0,stream>>>(FP(IWg[0]), FP(ILw[0]), shift, cst, FIN);
    k_we16<<<40,256,0,stream>>>(FP(IWe[0]), We16);
    k_gemm<<<gg,512,0,stream>>>(xbf, KP1, Wt, cst, buf0, bufA);
    k_sdot<<<gsd,256,0,stream>>>(buf0, FP(IAttn[0]), ssrc, sdst);
    k_q<<<1,64,0,stream>>>(FP(IWe[0]), FP(IAttn[0]), qbuf);
    k_logits<<<G(EE*4),256,0,stream>>>(ei, FP(2), qbuf, FP(IAt[0]), ssrc, sdst, L);
    k_mden<<<G(NN*4),256,0,stream>>>(iptr, eid, FP(2), L, cw);
    k_gath<<<(NN+NB-1)/NB,256,0,stream>>>(buf0, ei, iptr, eid, L, cw,
                                          We16, FP(ICb[0]), bufA);
  }
  // ---- layer 2 (A = bufA, K=1024) ----
  {
    hipMemsetAsync(stats, 0, 2*HID*sizeof(float), stream);
    dim3 bg(200, 4);
    k_bnstats<u16><<<bg,256,0,stream>>>(bufA, stats, HID);
    k_bnfin<<<4,256,0,stream>>>(stats, FP(IG[1]), FP(IB[1]), scale, shift, HID);
    dim3 ft(HID/32, 64);
    k_foldT<<<ft,256,0,stream>>>(FP(IWg[1]), FP(ILw[1]), scale, Wt, HID, HID);
    k_cinit<<<8,256,0,stream>>>(FP(ILb[1]), cst);
    dim3 cg(32, HID/128);
    k_const<<<cg,256,0,stream>>>(FP(IWg[1]), FP(ILw[1]), shift, cst, HID);
    k_we16<<<40,256,0,stream>>>(FP(IWe[1]), We16);
    k_gemm<<<gg,512,0,stream>>>(bufA, HID, Wt, cst, buf0, bufB);
    k_sdot<<<gsd,256,0,stream>>>(buf0, FP(IAttn[1]), ssrc, sdst);
    k_q<<<1,64,0,stream>>>(FP(IWe[1]), FP(IAttn[1]), qbuf);
    k_logits<<<G(EE*4),256,0,stream>>>(ei, FP(2), qbuf, FP(IAt[1]), ssrc, sdst, L);
    k_mden<<<G(NN*4),256,0,stream>>>(iptr, eid, FP(2), L, cw);
    k_gath<<<(NN+NB-1)/NB,256,0,stream>>>(buf0, ei, iptr, eid, L, cw,
                                          We16, FP(ICb[1]), bufB);
  }

  // ---- layer 3 (input = bufB) ----
  hipMemsetAsync(stats, 0, 2*HID*sizeof(float), stream);
  dim3 bg3(200, 4);
  k_bnstats<u16><<<bg3,256,0,stream>>>(bufB, stats, HID);
  k_bnfin<<<4,256,0,stream>>>(stats, FP(IG[2]), FP(IB[2]), scale, shift, HID);
  k_n3<<<NN,256,0,stream>>>(bufB, scale, shift, FP(IWg[2]), FP(ILw[2]), FP(ILb[2]),
                            FP(IAttn[2]), hg3, lin3, ssrc, sdst);
  k_logits3<<<G(EE),256,0,stream>>>(ei, FP(2), FP(IWe[2]), FP(IAttn[2]), FP(IAt[2]), ssrc, sdst, L);
  k_mden3<<<G(NN),256,0,stream>>>(iptr, eid, FP(2), L, cw);
  k_gather3<<<G(NN),256,0,stream>>>(ei, iptr, eid, L, cw, hg3,
                                    FP(IWe[2]), lin3, FP(ICb[2]), (float*)d_out);
}